// Round 7
// baseline (279.811 us; speedup 1.0000x reference)
//
#include <hip/hip_runtime.h>

// MatchNet: MLP -> batched PDHG LP solve. B=2048 rows; m=128; n=512; 60 iters.
// Solve: 1024 blocks x 512 thr, 2 batch rows/block. 2 barriers/iter.
//   - publish {A=2z-x, B=2u} per struct as {A0,A1,B0,B1}; Sxb = SA + sc*SB.
//   - row gather quad-split (row r <-> lanes 4r..4r+3), DPP quad-perm combine.
//   - index lists pre-unpacked u32 byte-offsets in REGISTERS.
//   - wave-uniform SALU guards from per-wave max counts (shfl_xor+readfirstlane).
//   - branchless iter-0 via red[60]=1e38 (sc==1.0) and virtual prev iterate.
// Prep: 4-block coalesced scan (col masks + transposed row bitmasks), then
// 1-block finish: list build (sorted by construction) + 31-iter power iter.

#define NC    128
#define NS    512
#define BATCH 2048
#define HID   20

typedef unsigned int  uint;
typedef unsigned short ushort;
typedef float v2f __attribute__((ext_vector_type(2)));

// ---------------- workspace layout (bytes) ----------------
// 0     : float tau
// 64    : u32 colmask[512*4]    (8192)   bit i of word g = S[32g+i][col]
// 8256  : u32 rowbits[128*16]   (8192)   bit c of word w = S[row][32w+c]
// 16448 : u32 col_meta[512*16]  (32768)  byte-offs (*8) into lam1_lds, pad->128*8
// 49216 : u32 col_cnt[512]      (2048)   even, <=16
// 51264 : u32 row_meta[512*12]  (24576)  per (row,quad): byte-offs (*16), pad->512*16
// 75840 : u32 row_cnt[512]      (2048)   even, <=10

template <int CTRL, int RMASK = 0xf>
__device__ __forceinline__ float dppadd(float s) {
    return s + __builtin_bit_cast(float,
        __builtin_amdgcn_update_dpp(0, __builtin_bit_cast(int, s), CTRL, RMASK, 0xf, true));
}
__device__ __forceinline__ float quad_sum(float s) {   // total in all 4 lanes of quad
    s = dppadd<0xB1>(s);   // quad_perm [1,0,3,2]
    s = dppadd<0x4E>(s);   // quad_perm [2,3,0,1]
    return s;
}
__device__ __forceinline__ float wave_sum_bcast(float x) {
    float s = x;
    s = dppadd<0x111>(s);  // row_shr:1
    s = dppadd<0x112>(s);  // row_shr:2
    s = dppadd<0x114>(s);  // row_shr:4
    s = dppadd<0x118>(s);  // row_shr:8
    s = dppadd<0x142, 0xa>(s);  // row_bcast:15
    s = dppadd<0x143, 0xc>(s);  // row_bcast:31
    return __builtin_bit_cast(float, __builtin_amdgcn_readlane(__builtin_bit_cast(int, s), 63));
}
__device__ __forceinline__ v2f vfma(v2f a, v2f b, v2f c) { return __builtin_elementwise_fma(a, b, c); }
__device__ __forceinline__ v2f vmax0(v2f a) { const v2f z = {0.f, 0.f}; return __builtin_elementwise_max(a, z); }
__device__ __forceinline__ v2f vmin0(v2f a) { const v2f z = {0.f, 0.f}; return __builtin_elementwise_min(a, z); }

// ---- prep 1: block g scans rows [32g,32g+32) x all 512 cols (coalesced) ----
__global__ __launch_bounds__(512) void prep_scan(
    const float* __restrict__ S, uint* __restrict__ colmask_g, uint* __restrict__ rowbits_g)
{
    __shared__ uint mcol[NS];
    const int t = threadIdx.x, g = blockIdx.x;
    float vals[32];
#pragma unroll
    for (int j = 0; j < 32; ++j) vals[j] = S[(g * 32 + j) * NS + t];
    uint m = 0;
#pragma unroll
    for (int j = 0; j < 32; ++j) if (vals[j] != 0.0f) m |= (1u << j);
    mcol[t] = m;
    colmask_g[t * 4 + g] = m;
    __syncthreads();
    const int j = t >> 4, w = t & 15;                  // 32 rows x 16 words
    uint val = 0;
#pragma unroll
    for (int c = 0; c < 32; ++c)
        val |= (((mcol[w * 32 + c] >> j) & 1u) << c);
    rowbits_g[(g * 32 + j) * 16 + w] = val;
}

// ---- prep 2: build lists + power iteration for tau ----
__global__ __launch_bounds__(512) void prep_finish(
    const uint* __restrict__ colmask_g, const uint* __restrict__ rowbits_g,
    float* __restrict__ tau_ws,
    uint* __restrict__ col_meta, uint* __restrict__ col_cnt_g,
    uint* __restrict__ row_meta, uint* __restrict__ row_cnt_g)
{
    __shared__ ushort clist[NS][16];
    __shared__ ushort rql[NS][10];
    __shared__ int    ccnt_l[NS];
    __shared__ int    rcnt_l[NS];
    __shared__ float  u_lds[NS + 1];
    __shared__ float  sv_lds[NC];
    __shared__ float  red_pi[32];
    const int t = threadIdx.x;

    uint cm[4];
    { const uint4 c4 = *(const uint4*)&colmask_g[t * 4];
      cm[0] = c4.x; cm[1] = c4.y; cm[2] = c4.z; cm[3] = c4.w; }
    // col list (ascending rows), byte-addrs *8 into lam1_lds; pad -> 128*8
    {
        int cc = 0;
#pragma unroll
        for (int g = 0; g < 4; ++g) {
            uint m = cm[g];
            while (m) {
                const int b = __ffs(m) - 1; m &= m - 1;
                if (cc < 16) clist[t][cc] = (ushort)((g * 32 + b) * 8);
                ++cc;
            }
        }
        if (cc > 16) cc = 16;
        const int cc2 = (cc + 1) & ~1;
        for (int k = cc; k < 16; ++k) clist[t][k] = (ushort)(NC * 8);
        ccnt_l[t] = cc2;
    }
    // row quarter lists (entry e -> quarter e&3), byte-addrs *16 into ab_lds
    if (t < NC) {
#pragma unroll
        for (int q = 0; q < 4; ++q)
            for (int p = 0; p < 10; ++p) rql[t * 4 + q][p] = (ushort)(NS * 16);
        uint rb[16];
        { const uint4 a = *(const uint4*)&rowbits_g[t * 16];
          const uint4 b = *(const uint4*)&rowbits_g[t * 16 + 4];
          const uint4 c = *(const uint4*)&rowbits_g[t * 16 + 8];
          const uint4 d = *(const uint4*)&rowbits_g[t * 16 + 12];
          rb[0]=a.x; rb[1]=a.y; rb[2]=a.z;  rb[3]=a.w;  rb[4]=b.x;  rb[5]=b.y;  rb[6]=b.z;  rb[7]=b.w;
          rb[8]=c.x; rb[9]=c.y; rb[10]=c.z; rb[11]=c.w; rb[12]=d.x; rb[13]=d.y; rb[14]=d.z; rb[15]=d.w; }
        int e = 0;
#pragma unroll
        for (int w = 0; w < 16; ++w) {
            uint m = rb[w];
            while (m) {
                const int b = __ffs(m) - 1; m &= m - 1;
                const int q = e & 3, p = e >> 2;
                if (p < 10) rql[t * 4 + q][p] = (ushort)((w * 32 + b) * 16);
                ++e;
            }
        }
#pragma unroll
        for (int q = 0; q < 4; ++q) {
            int n = (e - q + 3) >> 2;
            if (n < 0) n = 0;
            if (n > 10) n = 10;
            rcnt_l[t * 4 + q] = (n + 1) & ~1;
        }
    }
    if (t == 0) u_lds[NS] = 0.0f;
    if (t < 32) red_pi[t] = 0.0f;
    u_lds[t] = 1.0f;
    __syncthreads();

    // export (u32 unpacked byte-offsets)
    {
        col_cnt_g[t] = (uint)ccnt_l[t];
#pragma unroll
        for (int k = 0; k < 16; ++k) col_meta[t * 16 + k] = (uint)clist[t][k];
        row_cnt_g[t] = (uint)rcnt_l[t];
#pragma unroll
        for (int k = 0; k < 12; ++k)
            row_meta[t * 12 + k] = (k < 10) ? (uint)rql[t][k] : (uint)(NS * 16);
    }

    // power iteration: 31 iters, quad-split rows, 2 barriers/iter
    const int rcn = rcnt_l[t];
    float u_loc = 1.0f;
    for (int it = 0; it <= 30; ++it) {
        const float inv = it ? rsqrtf(red_pi[it - 1]) : 1.0f;
        float s = 0.0f;
        for (int k = 0; k < rcn; ++k) {
            const uint a = rql[t][k];
            s += *(const float*)((const char*)u_lds + (a >> 2));   // *16 -> *4
        }
        s = quad_sum(s * inv);
        if ((t & 3) == 3) sv_lds[t >> 2] = s;
        __syncthreads();
        const float vt = u_loc * inv;
        float w = vt;
#pragma unroll
        for (int g = 0; g < 4; ++g) {
            uint m = cm[g];
            while (m) { const int b = __ffs(m) - 1; m &= m - 1; w += sv_lds[g * 32 + b]; }
        }
        float p = (it < 30) ? w * w : w * vt;
        p = wave_sum_bcast(p);
        if ((t & 63) == 0) atomicAdd(&red_pi[it], p);
        u_lds[t] = w;
        u_loc = w;
        __syncthreads();
    }
    if (t == 0) tau_ws[0] = 0.9f / sqrtf(red_pi[30]);
}

// ---- main solve ----
__global__ __launch_bounds__(512, 8) void solve_kernel(
    const float* __restrict__ X,
    const float* __restrict__ W1, const float* __restrict__ b1,
    const float* __restrict__ W2, const float* __restrict__ b2,
    const float* __restrict__ W3, const float* __restrict__ b3,
    const float* __restrict__ W4, const float* __restrict__ b4,
    const float* __restrict__ tau_ws,
    const uint* __restrict__ col_meta, const uint* __restrict__ col_cnt_g,
    const uint* __restrict__ row_meta, const uint* __restrict__ row_cnt_g,
    float* __restrict__ out)
{
    __shared__ alignas(16) float4 ab_lds[NS + 1];     // {A0,A1,B0,B1} per struct
    __shared__ alignas(16) float2 lam1_lds[NC + 1];
    __shared__ alignas(16) float  red[61][2];         // slot 60 = 1e38 (iter -1)
    __shared__ alignas(16) float2 b_lds[NC];
    __shared__ float ha[2][HID], hb[2][HID];

    const int t  = threadIdx.x;
    const int r0 = blockIdx.x * 2, r1 = r0 + 1;

    // lists -> registers, pre-unpacked u32 byte offsets
    uint4 cA, cB, cC, cD, rA, rB, rC;
    { const uint4* g = (const uint4*)&col_meta[t * 16];
      cA = g[0]; cB = g[1]; cC = g[2]; cD = g[3]; }
    { const uint4* g = (const uint4*)&row_meta[t * 12];
      rA = g[0]; rB = g[1]; rC = g[2]; }
    int ccv = (int)col_cnt_g[t];
    int rcv = (int)row_cnt_g[t];

    if (t == 0) { ab_lds[NS] = make_float4(0,0,0,0); lam1_lds[NC] = make_float2(0,0); }
    if (t < 122) ((float*)red)[t] = (t >= 120) ? 1e38f : 0.0f;
    if (t < NC) b_lds[t] = make_float2(X[r0 * NC + t], X[r1 * NC + t]);

    // wave-uniform max counts -> SALU guards
#pragma unroll
    for (int off = 32; off; off >>= 1) {
        ccv = max(ccv, __shfl_xor(ccv, off));
        rcv = max(rcv, __shfl_xor(rcv, off));
    }
    const int cmax = __builtin_amdgcn_readfirstlane(ccv);
    const int rmax = __builtin_amdgcn_readfirstlane(rcv);
    __syncthreads();

    // MLP (two rows on threads 0..39)
    if (t < 2 * HID) {
        const int rr = t >= HID, tt = t - rr * HID;
        float s = b1[tt];
        for (int k = 0; k < NC; ++k)
            s = fmaf(rr ? b_lds[k].y : b_lds[k].x, W1[k * HID + tt], s);
        ha[rr][tt] = tanhf(s);
    }
    __syncthreads();
    if (t < 2 * HID) {
        const int rr = t >= HID, tt = t - rr * HID;
        float s = b2[tt];
        for (int k = 0; k < HID; ++k) s = fmaf(ha[rr][k], W2[k * HID + tt], s);
        hb[rr][tt] = tanhf(s);
    }
    __syncthreads();
    if (t < 2 * HID) {
        const int rr = t >= HID, tt = t - rr * HID;
        float s = b3[tt];
        for (int k = 0; k < HID; ++k) s = fmaf(hb[rr][k], W3[k * HID + tt], s);
        ha[rr][tt] = tanhf(s);
    }
    __syncthreads();
    float z0 = b4[t], z1 = z0;
    for (int h = 0; h < HID; ++h) {
        const float w = W4[h * NS + t];
        z0 = fmaf(ha[0][h], w, z0);
        z1 = fmaf(ha[1][h], w, z1);
    }

    const float tau = tau_ws[0];
    const float c10 = 10.0f * tau;
    const v2f tauv = {tau, tau};
    const v2f sigv = tauv;
    const int r = t >> 2, q = t & 3;
    const v2f bb = {b_lds[r].x, b_lds[r].y};

    const v2f z  = {z0, z1};
    const v2f z2 = z + z;
    v2f x  = vmax0(z);
    v2f u  = x - z;             // virtual prev iterate: sc==1 reproduces iter-0 init
    v2f A  = z2 - x;
    v2f Bv = u + u;
    v2f l1 = {0.f, 0.f};
    v2f l2 = {0.f, 0.f};
    ((v2f*)&ab_lds[t])[0] = A;
    ((v2f*)&ab_lds[t])[1] = Bv;
    __syncthreads();

    const char* abB = (const char*)ab_lds;
    const char* lmB = (const char*)lam1_lds;
    int prev = 60;
    for (int it = 0; it < 60; ++it) {
        // --- finish prev iter's primal update ---
        const float2 rr2 = *(const float2*)red[prev];
        const v2f sc = {fmaxf(0.f, 1.f - c10 * rsqrtf(rr2.x)),
                        fmaxf(0.f, 1.f - c10 * rsqrtf(rr2.y))};
        x = vfma(sc, u, z);
        const v2f xb = vfma(sc, Bv, A);
        l2 = vmin0(vfma(sigv, xb, l2));
        // --- row gather (quad-split, all 512 lanes, SALU guards) ---
        v2f gA = {0.f, 0.f}, gB = {0.f, 0.f};
#define RG(O1, O2) { const float4 g1 = *(const float4*)(abB + (O1));           \
                     const float4 g2 = *(const float4*)(abB + (O2));           \
                     gA += (v2f){g1.x, g1.y}; gB += (v2f){g1.z, g1.w};         \
                     gA += (v2f){g2.x, g2.y}; gB += (v2f){g2.z, g2.w}; }
        RG(rA.x, rA.y)
        RG(rA.z, rA.w)
        if (rmax > 4)  { RG(rB.x, rB.y) }
        if (rmax > 6)  { RG(rB.z, rB.w) }
        if (rmax > 8)  { RG(rC.x, rC.y) }
#undef RG
        const v2f gs = vfma(sc, gB, gA);
        const v2f sv = {quad_sum(gs.x), quad_sum(gs.y)};
        l1 = vmax0(vfma(sigv, sv - bb, l1));
        if (q == 3) lam1_lds[r] = make_float2(l1.x, l1.y);
        __syncthreads();                                  // lam1 ready
        // --- col gather + primal prox prep ---
        v2f s2 = {0.f, 0.f};
#define CG(O1, O2) { s2 += *(const v2f*)(lmB + (O1));                          \
                     s2 += *(const v2f*)(lmB + (O2)); }
        CG(cA.x, cA.y)
        CG(cA.z, cA.w)
        if (cmax > 4)  { CG(cB.x, cB.y) }
        if (cmax > 6)  { CG(cB.z, cB.w) }
        if (cmax > 8)  { CG(cC.x, cC.y) }
        if (cmax > 10) { CG(cC.z, cC.w) }
        if (cmax > 12) { CG(cD.x, cD.y) }
        if (cmax > 14) { CG(cD.z, cD.w) }
#undef CG
        const v2f v = x - tauv * (s2 + l2);
        u  = (v + tauv) - z;
        A  = z2 - x;
        Bv = u + u;
        ((v2f*)&ab_lds[t])[0] = A;
        ((v2f*)&ab_lds[t])[1] = Bv;
        const v2f p = u * u;
        const float p0 = wave_sum_bcast(p.x);
        const float p1 = wave_sum_bcast(p.y);
        if ((t & 63) == 0) { atomicAdd(&red[it][0], p0); atomicAdd(&red[it][1], p1); }
        prev = it;
        __syncthreads();                                  // A/B + red ready
    }
    const float2 rr2 = *(const float2*)red[59];
    const v2f sc = {fmaxf(0.f, 1.f - c10 * rsqrtf(rr2.x)),
                    fmaxf(0.f, 1.f - c10 * rsqrtf(rr2.y))};
    const v2f xf = vfma(sc, u, z);
    out[r0 * NS + t] = xf.x;
    out[r1 * NS + t] = xf.y;
}

extern "C" void kernel_launch(void* const* d_in, const int* in_sizes, int n_in,
                              void* d_out, int out_size, void* d_ws, size_t ws_size,
                              hipStream_t stream)
{
    const float* X  = (const float*)d_in[0];
    const float* W1 = (const float*)d_in[1];
    const float* b1 = (const float*)d_in[2];
    const float* W2 = (const float*)d_in[3];
    const float* b2 = (const float*)d_in[4];
    const float* W3 = (const float*)d_in[5];
    const float* b3 = (const float*)d_in[6];
    const float* W4 = (const float*)d_in[7];
    const float* b4 = (const float*)d_in[8];
    const float* S  = (const float*)d_in[9];
    float* out = (float*)d_out;

    char* ws = (char*)d_ws;
    float* tau_ws    = (float*)(ws + 0);
    uint*  colmask_g = (uint*)(ws + 64);
    uint*  rowbits_g = (uint*)(ws + 8256);
    uint*  col_meta  = (uint*)(ws + 16448);
    uint*  col_cnt_g = (uint*)(ws + 49216);
    uint*  row_meta  = (uint*)(ws + 51264);
    uint*  row_cnt_g = (uint*)(ws + 75840);

    prep_scan<<<4, 512, 0, stream>>>(S, colmask_g, rowbits_g);
    prep_finish<<<1, 512, 0, stream>>>(colmask_g, rowbits_g, tau_ws,
                                       col_meta, col_cnt_g, row_meta, row_cnt_g);
    solve_kernel<<<BATCH / 2, 512, 0, stream>>>(X, W1, b1, W2, b2, W3, b3, W4, b4,
                                                tau_ws, col_meta, col_cnt_g,
                                                row_meta, row_cnt_g, out);
}